// Round 14
// baseline (288.790 us; speedup 1.0000x reference)
//
#include <hip/hip_runtime.h>
#include <hip/hip_bf16.h>

typedef __attribute__((ext_vector_type(8))) short s16x8;
typedef __attribute__((ext_vector_type(4))) float f32x4;
typedef __attribute__((ext_vector_type(16))) float f32x16;
typedef __attribute__((ext_vector_type(4))) unsigned short us4;
typedef __attribute__((ext_vector_type(4))) unsigned int u32x4;

#define MFMA16(a,b,c) __builtin_amdgcn_mfma_f32_16x16x32_bf16((a),(b),(c),0,0,0)
#define MFMA32(a,b,c) __builtin_amdgcn_mfma_f32_32x32x16_bf16((a),(b),(c),0,0,0)

__device__ __forceinline__ float b2f(unsigned short u){
  union{unsigned u; float f;} v; v.u = ((unsigned)u)<<16; return v.f;
}
__device__ __forceinline__ unsigned short f2b(float f){
  union{float f; unsigned u;} v; v.f = f;
  unsigned r = v.u + 0x7fffu + ((v.u>>16)&1u);
  return (unsigned short)(r>>16);
}
__device__ __forceinline__ unsigned cvt_pk_bf16(float lo, float hi){
  unsigned r;
  asm volatile("v_cvt_pk_bf16_f32 %0, %1, %2" : "=v"(r) : "v"(lo), "v"(hi));
  return r;
}

__device__ __forceinline__ void gl_lds16(const void* gp, void* lp){
  __builtin_amdgcn_global_load_lds((const __attribute__((address_space(1))) void*)gp,
                                   (__attribute__((address_space(3))) void*)lp, 16, 0, 0);
}

// ---- 256-thread staging helper (GEMM kernels, swizzled rows) ----
__device__ __forceinline__ void stage_64x256(void* lds, const unsigned short* g, int stride){
  const int t = threadIdx.x, wv = t>>6;
  #pragma unroll
  for (int i=0;i<8;++i){
    int ch = i*256 + t;
    int row = ch>>5, cc = ch&31, sc = cc ^ (row&7);
    gl_lds16((const char*)(g + (size_t)row*stride) + sc*16,
             (char*)lds + (((size_t)i*256 + wv*64)<<4));
  }
}
// ---- 512-thread linear 16KB block copy (attention octet tiles) ----
__device__ __forceinline__ void stage16KB(void* lds, const unsigned short* g){
  const int tid = threadIdx.x;
  #pragma unroll
  for (int i=0;i<2;++i){
    int ch = i*512 + tid;
    gl_lds16((const char*)(g + (size_t)ch*8), (char*)lds + (size_t)ch*16);
  }
}

// ---------------- f32 -> bf16 cast ----------------
__global__ void k_cvt(const float* __restrict__ src, unsigned short* __restrict__ dst){
  int i = blockIdx.x*256 + threadIdx.x;
  f32x4 v = *(const f32x4*)(src + (size_t)i*4);
  us4 o;
  #pragma unroll
  for (int r=0;r<4;++r) o[r] = f2b(v[r]);
  *(us4*)(dst + (size_t)i*4) = o;
}

// ---------------- out_w f32 [o][c] -> octet bf16 Wo_oct[o>>5][c>>3][o&31][8] ----------------
__global__ void k_cvt_wo(const float* __restrict__ src, unsigned short* __restrict__ dst){
  int j = blockIdx.x*256 + threadIdx.x;   // 16384 threads x 4 elems
  int flat = j*4;
  int o = flat>>8, c = flat&255;
  f32x4 v = *(const f32x4*)(src + flat);
  us4 p;
  #pragma unroll
  for (int r=0;r<4;++r) p[r] = f2b(v[r]);
  size_t idx = (size_t)(o>>5)*8192 + (size_t)(c>>3)*256 + (o&31)*8 + (c&7);
  *(us4*)(dst + idx) = p;
}

// ---------------- transpose+cast x[b][c][n] (f32) -> Xt[b][n][c] (bf16) + gray partials ----------------
__global__ void k_transpose(const float* __restrict__ xg, unsigned short* __restrict__ Xtg,
                            float* __restrict__ gray4){
  __shared__ unsigned short T[64*68];
  __shared__ float psum[4*64];
  const int nb = blockIdx.x, cb = blockIdx.y, b = blockIdx.z;
  const int n0 = nb*64, c0 = cb*64;
  const int t = threadIdx.x;
  #pragma unroll
  for (int i=0;i<4;++i){
    int idx = i*256 + t;
    int c = idx>>4, k4 = idx&15;
    f32x4 v = *(const f32x4*)(xg + ((size_t)(b*256 + c0 + c))*4096 + n0 + k4*4);
    us4 o;
    #pragma unroll
    for (int r=0;r<4;++r) o[r] = f2b(v[r]);
    *(us4*)&T[c*68 + k4*4] = o;
  }
  __syncthreads();
  #pragma unroll
  for (int i=0;i<2;++i){
    int idx = i*256 + t;
    int n = idx>>3, ck = idx&7;
    unsigned short vv[8];
    #pragma unroll
    for (int j=0;j<8;++j) vv[j] = T[(ck*8+j)*68 + n];
    *(u32x4*)(Xtg + ((size_t)(b*4096 + n0 + n))*256 + c0 + ck*8) = *(const u32x4*)vv;
  }
  // gray partial: sum this block's 64 channels per n
  {
    int j = t&63, q = t>>6;
    float s = 0.f;
    #pragma unroll
    for (int c16=0;c16<16;++c16) s += b2f(T[(q*16+c16)*68 + j]);
    psum[q*64 + j] = s;
  }
  __syncthreads();
  if (t < 64){
    float s = psum[t] + psum[64+t] + psum[128+t] + psum[192+t];
    gray4[((size_t)(cb*8 + b))*4096 + n0 + t] = s;
  }
}

// ---------------- fused density chain: gray -> |lap| -> conv8+relu -> conv1+sigmoid -> scale ----------------
__global__ __launch_bounds__(256) void k_density(const float* __restrict__ gray4,
    const float* __restrict__ w1, const float* __restrict__ b1,
    const float* __restrict__ w2, const float* __restrict__ b2_,
    float* __restrict__ sc2){
  __shared__ float gf[4096];
  __shared__ float la[4096];
  __shared__ unsigned short hb[8*4096];
  const int b = blockIdx.x, t = threadIdx.x;
  #pragma unroll
  for (int i=0;i<16;++i){
    int px = i*256 + t;
    float s = gray4[(size_t)(0*8+b)*4096 + px] + gray4[(size_t)(1*8+b)*4096 + px]
            + gray4[(size_t)(2*8+b)*4096 + px] + gray4[(size_t)(3*8+b)*4096 + px];
    gf[px] = s * (1.f/256.f);
  }
  __syncthreads();
  #pragma unroll
  for (int i=0;i<16;++i){
    int px = i*256 + t;
    int hh = px>>6, ww = px&63;
    float c = gf[px];
    float up = hh>0  ? gf[px-64] : 0.f;
    float dn = hh<63 ? gf[px+64] : 0.f;
    float lf = ww>0  ? gf[px-1]  : 0.f;
    float rt = ww<63 ? gf[px+1]  : 0.f;
    la[px] = fabsf(4.f*c - up - dn - lf - rt);
  }
  __syncthreads();
  float w1r[72], b1r[8];
  #pragma unroll
  for (int k=0;k<72;++k) w1r[k] = w1[k];
  #pragma unroll
  for (int j=0;j<8;++j) b1r[j] = b1[j];
  #pragma unroll
  for (int i=0;i<16;++i){
    int px = i*256 + t;
    int hh = px>>6, ww = px&63;
    float tap[9];
    #pragma unroll
    for (int dy=-1;dy<=1;++dy)
      #pragma unroll
      for (int dx=-1;dx<=1;++dx){
        int y=hh+dy, x2=ww+dx;
        tap[(dy+1)*3+dx+1] = (y>=0&&y<64&&x2>=0&&x2<64)? la[y*64+x2] : 0.f;
      }
    #pragma unroll
    for (int j=0;j<8;++j){
      float a = b1r[j];
      #pragma unroll
      for (int k=0;k<9;++k) a += w1r[j*9+k]*tap[k];
      hb[j*4096 + px] = f2b(fmaxf(a, 0.f));
    }
  }
  __syncthreads();
  float w2r[72], b20 = b2_[0];
  #pragma unroll
  for (int k=0;k<72;++k) w2r[k] = w2[k];
  #pragma unroll
  for (int i=0;i<16;++i){
    int px = i*256 + t;
    int hh = px>>6, ww = px&63;
    float a = b20;
    #pragma unroll
    for (int j=0;j<8;++j){
      #pragma unroll
      for (int dy=-1;dy<=1;++dy)
        #pragma unroll
        for (int dx=-1;dx<=1;++dx){
          int y=hh+dy, x2=ww+dx;
          if (y>=0&&y<64&&x2>=0&&x2<64) a += w2r[j*9+(dy+1)*3+(dx+1)]*b2f(hb[j*4096 + y*64+x2]);
        }
    }
    float sig = 1.f/(1.f+__expf(-a));
    sc2[(size_t)b*4096 + px] = 0.09016844f/(3.f - 2.f*sig);   // C^-0.5 * log2e / temp
  }
}

// ---------------- QKV GEMM: block owns one n-tile, loops all 12 W-tiles ----------------
// Q -> Q[n][c] row-major; K -> octet blocks Koct[b][m>>5][c>>3][m&31][8];
// V -> octet blocks Voct[b][m>>5][(m&31)>>3][c][m&7]
__global__ __launch_bounds__(256,2) void k_gemm_qkv(const unsigned short* __restrict__ Wg,
    const unsigned short* __restrict__ Xtg, const float* __restrict__ biasg,
    unsigned short* __restrict__ Qo, unsigned short* __restrict__ Ko, unsigned short* __restrict__ Vto){
  __shared__ unsigned short Xl[64*256];   // staged once per block
  __shared__ unsigned short Wl[64*256];   // re-staged per at-tile
  const int nt_ = blockIdx.x, b = blockIdx.y;
  const int n0 = nt_*64;
  stage_64x256(Xl, Xtg + ((size_t)(b*4096 + n0))*256, 256);
  const int t = threadIdx.x, w = t>>6, lane = t&63, lam = lane&15, lg = lane>>4;
  f32x4 zz = {0.f,0.f,0.f,0.f};
  for (int at=0; at<12; ++at){
    const int a0 = at*64;
    stage_64x256(Wl, Wg + (size_t)a0*256, 256);
    __syncthreads();                       // Wl (and Xl on first iter) staged
    f32x4 acc[4] = {zz,zz,zz,zz};
    #pragma unroll
    for (int u=0;u<8;++u){
      int ar = 16*w + lam;
      s16x8 af = *(const s16x8*)((const char*)Wl + ar*512 + ((64*u+16*lg) ^ ((ar&7)<<4)));
      #pragma unroll
      for (int ct=0;ct<4;++ct){
        int br = 16*ct + lam;
        s16x8 bf = *(const s16x8*)((const char*)Xl + br*512 + ((64*u+16*lg) ^ ((br&7)<<4)));
        acc[ct] = MFMA16(af, bf, acc[ct]);
      }
    }
    const int ob = a0 + 16*w + 4*lg;
    f32x4 bias4 = *(const f32x4*)(biasg + ob);
    #pragma unroll
    for (int ct=0;ct<4;++ct){
      int n = n0 + 16*ct + lam;
      us4 ov;
      #pragma unroll
      for (int r=0;r<4;++r) ov[r] = f2b(acc[ct][r] + bias4[r]);
      if (a0 < 256){
        *(us4*)(Qo + ((size_t)(b*4096 + n))*256 + ob) = ov;        // Q[n][c]
      } else if (a0 < 512){
        int c4 = ob - 256;
        size_t idx = (((size_t)(b*128 + (n>>5))*1024) + (c4>>3)*32 + (n&31))*8 + (c4&7);
        *(us4*)(Ko + idx) = ov;
      } else {
        int c0v = ob - 512;
        size_t base = ((size_t)(b*128 + (n>>5))*1024 + ((n&31)>>3)*256)*8 + (n&7);
        #pragma unroll
        for (int r=0;r<4;++r)
          Vto[base + (size_t)(c0v+r)*8] = ov[r];
      }
    }
    __syncthreads();                       // all waves done reading Wl before overwrite
  }
}

// ---------------- flash attention (R10 loop) + fused out-GEMM epilogue ----------------
__global__ __launch_bounds__(512,2) void k_attn(const unsigned short* __restrict__ Qg,
    const unsigned short* __restrict__ Kg, const unsigned short* __restrict__ Vtg,
    const float* __restrict__ Sg, const unsigned short* __restrict__ WoG,
    const float* __restrict__ obias, const float* __restrict__ xg,
    float* __restrict__ outg){
  __shared__ __align__(16) char SL[132096];
  unsigned short* Kl = (unsigned short*)SL;             // [buf][grp] 16KB octet tiles
  unsigned short* Vl = (unsigned short*)(SL + 65536);
  float* mlb = (float*)(SL + 131072);                   // [4][32][2]
  float* Ob  = (float*)SL;                              // merge reuse [4][32][256] f32
  unsigned short* AOl = (unsigned short*)SL;            // epilogue: 64KB octet AO
  unsigned short* WoL = (unsigned short*)(SL + 65536);  // epilogue: 64KB Wo half

  const int tid = threadIdx.x, w = tid>>6, lane = tid&63, l31 = lane&31, h = lane>>5;
  const int g = w>>2;                      // key-half group
  const int bid = blockIdx.x;
  const int b = bid&7, qt = bid>>3;        // XCD-major: batch pinned to XCD
  const int qbase = qt*128 + (w&3)*32;

  const unsigned short* KgB = Kg  + (size_t)b*128*8192;   // octet blocks of 8192 elems
  const unsigned short* VtB = Vtg + (size_t)b*128*8192;
  const float* SgB = Sg + (size_t)b*4096 + g*2048;

  // Q fragments (B-operand): lane q-col=l31, k-elems 16u+8h..+7
  s16x8 qf[16];
  {
    const unsigned short* qp = Qg + ((size_t)(b*4096 + qbase + l31))*256 + 8*h;
    #pragma unroll
    for (int u=0;u<16;++u) qf[u] = *(const s16x8*)(qp + 16*u);
  }
  f32x16 oa[8];
  #pragma unroll
  for (int nb=0;nb<8;++nb)
    #pragma unroll
    for (int i=0;i<16;++i) oa[nb][i]=0.f;
  float m_run = 0.f, l_run = 0.f;          // log2 domain; m=0 valid start (defer-bounded)

  #define KBUF(bu,gr) (Kl + ((bu)*2+(gr))*8192)
  #define VBUF(bu,gr) (Vl + ((bu)*2+(gr))*8192)

  stage16KB(KBUF(0,0), KgB);
  stage16KB(KBUF(0,1), KgB + (size_t)64*8192);
  stage16KB(VBUF(0,0), VtB);
  stage16KB(VBUF(0,1), VtB + (size_t)64*8192);
  __syncthreads();

  int cur = 0;
  for (int t=0; t<64; ++t){
    // stage(t+1) at loop top: full iteration to complete (R7/R10 schedule)
    if (t < 63){
      stage16KB(KBUF(cur^1,0), KgB + (size_t)(t+1)*8192);
      stage16KB(KBUF(cur^1,1), KgB + (size_t)(64+t+1)*8192);
      stage16KB(VBUF(cur^1,0), VtB + (size_t)(t+1)*8192);
      stage16KB(VBUF(cur^1,1), VtB + (size_t)(64+t+1)*8192);
    }
    const char* Kc = (const char*)KBUF(cur,g);
    const char* Vc = (const char*)VBUF(cur,g);

    // per-key temperature scales (log2-domain, from k_density)
    f32x4 sv[4];
    {
      const float* Sp = SgB + t*32;
      #pragma unroll
      for (int j=0;j<4;++j) sv[j] = *(const f32x4*)(Sp + 8*j + 4*h);
    }

    // S^T = K * Q^T : D col=q=l31, row=key (r&3)+8*(r>>2)+4h
    f32x16 st;
    #pragma unroll
    for (int i=0;i<16;++i) st[i]=0.f;
    __builtin_amdgcn_s_setprio(1);
    #pragma unroll
    for (int u=0;u<16;++u){
      s16x8 kf = *(const s16x8*)(Kc + (((2*u+h)*32 + l31)<<4));
      st = MFMA32(kf, qf[u], st);
    }
    __builtin_amdgcn_s_setprio(0);

    float pm[16];
    #pragma unroll
    for (int j=0;j<4;++j)
      #pragma unroll
      for (int i=0;i<4;++i) pm[4*j+i] = st[4*j+i]*sv[j][i];

    // max tree -> defer check -> single exp2
    float mx[8];
    #pragma unroll
    for (int i=0;i<8;++i) mx[i] = fmaxf(pm[i], pm[8+i]);
    #pragma unroll
    for (int i=0;i<4;++i) mx[i] = fmaxf(mx[i], mx[4+i]);
    float tmax = fmaxf(fmaxf(mx[0],mx[1]), fmaxf(mx[2],mx[3]));
    if (__any(tmax > m_run + 11.5415603f)){   // defer-max (rare)
      tmax = fmaxf(tmax, __shfl_xor(tmax, 32));
      float mnew = fmaxf(m_run, tmax);
      float fs = exp2f(m_run - mnew);
      m_run = mnew;
      l_run *= fs;
      float fr[16];
      #pragma unroll
      for (int r=0;r<16;++r) fr[r] = __shfl(fs, (r&3)+8*(r>>2)+4*h);
      #pragma unroll
      for (int nb=0;nb<8;++nb)
        #pragma unroll
        for (int r=0;r<16;++r) oa[nb][r] *= fr[r];
    }
    float pe[16];
    #pragma unroll
    for (int i=0;i<16;++i) pe[i] = exp2f(pm[i] - m_run);
    {
      float sm[8];
      #pragma unroll
      for (int i=0;i<8;++i) sm[i] = pe[i] + pe[8+i];
      #pragma unroll
      for (int i=0;i<4;++i) sm[i] += sm[4+i];
      float rs = (sm[0]+sm[1])+(sm[2]+sm[3]);
      rs += __shfl_xor(rs, 32);
      l_run += rs;
    }

    // pack P to bf16 quads via cvt_pk: pq[2j],pq[2j+1] = keys 8j+4h+0..3
    unsigned pq[8];
    #pragma unroll
    for (int j=0;j<4;++j){
      pq[2*j]   = cvt_pk_bf16(pe[4*j],   pe[4*j+1]);
      pq[2*j+1] = cvt_pk_bf16(pe[4*j+2], pe[4*j+3]);
    }

    // PV: A-frag assembled in-register via cross-h swap; B=V^T octet tile
    __builtin_amdgcn_s_setprio(1);
    #pragma unroll
    for (int ks=0;ks<2;++ks){
      const int j0 = 2*ks, j1 = 2*ks+1;
      unsigned s0 = h ? pq[2*j0]   : pq[2*j1];
      unsigned s1 = h ? pq[2*j0+1] : pq[2*j1+1];
      unsigned r0 = (unsigned)__shfl_xor((int)s0, 32);
      unsigned r1 = (unsigned)__shfl_xor((int)s1, 32);
      union { unsigned u[4]; s16x8 v; } pa;
      pa.u[0] = h ? r0 : pq[2*j0];
      pa.u[1] = h ? r1 : pq[2*j0+1];
      pa.u[2] = h ? pq[2*j1]   : r0;
      pa.u[3] = h ? pq[2*j1+1] : r1;
      #pragma unroll
      for (int nb=0;nb<8;++nb){
        s16x8 vf = *(const s16x8*)(Vc + (((2*ks+h)*256 + 32*nb + l31)<<4));
        oa[nb] = MFMA32(pa.v, vf, oa[nb]);
      }
    }
    __builtin_amdgcn_s_setprio(0);

    __syncthreads();
    cur ^= 1;
  }

  // ---- in-block merge of the two key-halves (log2-domain m) ----
  if (g == 1){
    if (h == 0){
      mlb[((w-4)*32 + l31)*2]   = m_run;
      mlb[((w-4)*32 + l31)*2+1] = l_run;
    }
    float* Ow = Ob + (size_t)(w-4)*32*256;
    #pragma unroll
    for (int nb=0;nb<8;++nb)
      #pragma unroll
      for (int r=0;r<16;++r){
        int qr = (r&3)+8*(r>>2)+4*h;
        Ow[qr*256 + 32*nb + l31] = oa[nb][r];
      }
  }
  __syncthreads();
  if (g == 0){
    const float* Or = Ob + (size_t)w*32*256;
    #pragma unroll
    for (int r=0;r<16;++r){
      int qr = (r&3)+8*(r>>2)+4*h;
      float m0r = __shfl(m_run, qr);
      float l0r = __shfl(l_run, qr);
      float m1r = mlb[(w*32+qr)*2];
      float l1r = mlb[(w*32+qr)*2+1];
      float M = fmaxf(m0r, m1r);
      float a0 = exp2f(m0r - M), a1 = exp2f(m1r - M);
      float inv = 1.f/(l0r*a0 + l1r*a1);
      a0 *= inv; a1 *= inv;
      #pragma unroll
      for (int nb=0;nb<8;++nb)
        oa[nb][r] = oa[nb][r]*a0 + Or[qr*256 + 32*nb + l31]*a1;
    }
  }
  __syncthreads();   // Ob reads complete; LDS free for AOl/WoL

  // ---- AOl (octet bf16) write by g==0 | Wo half0 stage by g==1 ----
  if (g == 0){
    #pragma unroll
    for (int nb=0;nb<8;++nb){
      #pragma unroll
      for (int r=0;r<16;++r){
        int qr = (r&3)+8*(r>>2)+4*h;
        int c = 32*nb + l31;
        AOl[(size_t)w*8192 + ((c>>3)*32 + qr)*8 + (c&7)] = f2b(oa[nb][r]);
      }
    }
  } else {
    int tl = tid - 256;
    #pragma unroll
    for (int i=0;i<16;++i){
      int ch = i*256 + tl;
      gl_lds16((const char*)(WoG + (size_t)ch*8), (char*)WoL + (size_t)ch*16);
    }
  }
  __syncthreads();

  // ---- out-GEMM: out[o][n] = Wo[o][c]*AO[n][c] + bias + x, two o-halves ----
  #pragma unroll
  for (int half=0; half<2; ++half){
    if (half){
      __syncthreads();   // all reads of WoL half0 done
      #pragma unroll
      for (int i=0;i<8;++i){
        int ch = i*512 + tid;
        gl_lds16((const char*)(WoG + (size_t)32768 + (size_t)ch*8), (char*)WoL + (size_t)ch*16);
      }
      __syncthreads();
    }
    #pragma unroll
    for (int rep=0; rep<2; ++rep){
      int tile = w*2 + rep;           // 0..15
      int nt2 = tile & 3, ot = tile >> 2;
      f32x16 acc;
      #pragma unroll
      for (int i=0;i<16;++i) acc[i] = 0.f;
      __builtin_amdgcn_s_setprio(1);
      #pragma unroll
      for (int u=0;u<16;++u){
        s16x8 af = *(const s16x8*)((const char*)WoL + ot*16384 + (((2*u+h)*32 + l31)<<4));
        s16x8 bf = *(const s16x8*)((const char*)AOl + nt2*16384 + (((2*u+h)*32 + l31)<<4));
        acc = MFMA32(af, bf, acc);
      }
      __builtin_amdgcn_s_setprio(0);
      #pragma unroll
      for (int r=0;r<16;++r){
        int o_g = half*128 + ot*32 + (r&3)+8*(r>>2)+4*h;
        int n_g = qt*128 + nt2*32 + l31;
        size_t base = ((size_t)(b*256 + o_g))*4096 + n_g;
        outg[base] = acc[r] + obias[o_g] + xg[base];
      }
    }
  }
  #undef KBUF
  #undef VBUF
}

extern "C" void kernel_launch(void* const* d_in, const int* in_sizes, int n_in,
                              void* d_out, int out_size, void* d_ws, size_t ws_size,
                              hipStream_t stream){
  const float* x     = (const float*)d_in[0];
  const float* qkv_w = (const float*)d_in[1];
  const float* qkv_b = (const float*)d_in[2];
  const float* out_w = (const float*)d_in[3];
  const float* out_b = (const float*)d_in[4];
  const float* d1_w  = (const float*)d_in[5];
  const float* d1_b  = (const float*)d_in[6];
  const float* d2_w  = (const float*)d_in[7];
  const float* d2_b  = (const float*)d_in[8];
  float* out = (float*)d_out;

  char* p = (char*)d_ws;
  const size_t BIG = (size_t)8*4096*256*2;
  unsigned short* Xt = (unsigned short*)p; p += BIG;
  unsigned short* Q  = (unsigned short*)p; p += BIG;
  unsigned short* K  = (unsigned short*)p; p += BIG;
  unsigned short* Vt = (unsigned short*)p; p += BIG;
  unsigned short* Wq = (unsigned short*)p; p += (size_t)768*256*2;
  unsigned short* Wo = (unsigned short*)p; p += (size_t)256*256*2;
  float* gray4 = (float*)p; p += (size_t)4*8*4096*4;
  float* sc    = (float*)p; p += (size_t)8*4096*4;

  k_cvt      <<<dim3(192),    256, 0, stream>>>(qkv_w, Wq);
  k_cvt_wo   <<<dim3(64),     256, 0, stream>>>(out_w, Wo);
  k_transpose<<<dim3(64,4,8), 256, 0, stream>>>(x, Xt, gray4);
  k_density  <<<dim3(8),      256, 0, stream>>>(gray4, d1_w, d1_b, d2_w, d2_b, sc);
  k_gemm_qkv <<<dim3(64,8),   256, 0, stream>>>(Wq, Xt, qkv_b, Q, K, Vt);
  k_attn     <<<dim3(256),    512, 0, stream>>>(Q, K, Vt, sc, Wo, out_b, x, out);
}

// Round 15
// 278.009 us; speedup vs baseline: 1.0388x; 1.0388x over previous
//
#include <hip/hip_runtime.h>
#include <hip/hip_bf16.h>

typedef __attribute__((ext_vector_type(8))) short s16x8;
typedef __attribute__((ext_vector_type(4))) float f32x4;
typedef __attribute__((ext_vector_type(16))) float f32x16;
typedef __attribute__((ext_vector_type(4))) unsigned short us4;
typedef __attribute__((ext_vector_type(4))) unsigned int u32x4;

#define MFMA16(a,b,c) __builtin_amdgcn_mfma_f32_16x16x32_bf16((a),(b),(c),0,0,0)
#define MFMA32(a,b,c) __builtin_amdgcn_mfma_f32_32x32x16_bf16((a),(b),(c),0,0,0)

__device__ __forceinline__ float b2f(unsigned short u){
  union{unsigned u; float f;} v; v.u = ((unsigned)u)<<16; return v.f;
}
__device__ __forceinline__ unsigned short f2b(float f){
  union{float f; unsigned u;} v; v.f = f;
  unsigned r = v.u + 0x7fffu + ((v.u>>16)&1u);
  return (unsigned short)(r>>16);
}
__device__ __forceinline__ unsigned cvt_pk_bf16(float lo, float hi){
  unsigned r;
  asm volatile("v_cvt_pk_bf16_f32 %0, %1, %2" : "=v"(r) : "v"(lo), "v"(hi));
  return r;
}

__device__ __forceinline__ void gl_lds16(const void* gp, void* lp){
  __builtin_amdgcn_global_load_lds((const __attribute__((address_space(1))) void*)gp,
                                   (__attribute__((address_space(3))) void*)lp, 16, 0, 0);
}

// ---- 256-thread staging helper (GEMM kernels, swizzled rows) ----
__device__ __forceinline__ void stage_64x256(void* lds, const unsigned short* g, int stride){
  const int t = threadIdx.x, wv = t>>6;
  #pragma unroll
  for (int i=0;i<8;++i){
    int ch = i*256 + t;
    int row = ch>>5, cc = ch&31, sc = cc ^ (row&7);
    gl_lds16((const char*)(g + (size_t)row*stride) + sc*16,
             (char*)lds + (((size_t)i*256 + wv*64)<<4));
  }
}
// ---- 512-thread linear 16KB block copy (attention octet tiles) ----
__device__ __forceinline__ void stage16KB(void* lds, const unsigned short* g){
  const int tid = threadIdx.x;
  #pragma unroll
  for (int i=0;i<2;++i){
    int ch = i*512 + tid;
    gl_lds16((const char*)(g + (size_t)ch*8), (char*)lds + (size_t)ch*16);
  }
}

// ---------------- f32 -> bf16 cast ----------------
__global__ void k_cvt(const float* __restrict__ src, unsigned short* __restrict__ dst){
  int i = blockIdx.x*256 + threadIdx.x;
  f32x4 v = *(const f32x4*)(src + (size_t)i*4);
  us4 o;
  #pragma unroll
  for (int r=0;r<4;++r) o[r] = f2b(v[r]);
  *(us4*)(dst + (size_t)i*4) = o;
}

// ---------------- transpose+cast x[b][c][n] (f32) -> Xt[b][n][c] (bf16) + gray partials ----------------
__global__ void k_transpose(const float* __restrict__ xg, unsigned short* __restrict__ Xtg,
                            float* __restrict__ gray4){
  __shared__ unsigned short T[64*68];
  __shared__ float psum[4*64];
  const int nb = blockIdx.x, cb = blockIdx.y, b = blockIdx.z;
  const int n0 = nb*64, c0 = cb*64;
  const int t = threadIdx.x;
  #pragma unroll
  for (int i=0;i<4;++i){
    int idx = i*256 + t;
    int c = idx>>4, k4 = idx&15;
    f32x4 v = *(const f32x4*)(xg + ((size_t)(b*256 + c0 + c))*4096 + n0 + k4*4);
    us4 o;
    #pragma unroll
    for (int r=0;r<4;++r) o[r] = f2b(v[r]);
    *(us4*)&T[c*68 + k4*4] = o;
  }
  __syncthreads();
  #pragma unroll
  for (int i=0;i<2;++i){
    int idx = i*256 + t;
    int n = idx>>3, ck = idx&7;
    unsigned short vv[8];
    #pragma unroll
    for (int j=0;j<8;++j) vv[j] = T[(ck*8+j)*68 + n];
    *(u32x4*)(Xtg + ((size_t)(b*4096 + n0 + n))*256 + c0 + ck*8) = *(const u32x4*)vv;
  }
  // gray partial: sum this block's 64 channels per n
  {
    int j = t&63, q = t>>6;
    float s = 0.f;
    #pragma unroll
    for (int c16=0;c16<16;++c16) s += b2f(T[(q*16+c16)*68 + j]);
    psum[q*64 + j] = s;
  }
  __syncthreads();
  if (t < 64){
    float s = psum[t] + psum[64+t] + psum[128+t] + psum[192+t];
    gray4[((size_t)(cb*8 + b))*4096 + n0 + t] = s;
  }
}

// ---------------- fused density chain: gray -> |lap| -> conv8+relu -> conv1+sigmoid -> scale ----------------
__global__ __launch_bounds__(256) void k_density(const float* __restrict__ gray4,
    const float* __restrict__ w1, const float* __restrict__ b1,
    const float* __restrict__ w2, const float* __restrict__ b2_,
    float* __restrict__ sc2){
  __shared__ float gf[4096];
  __shared__ float la[4096];
  __shared__ unsigned short hb[8*4096];
  const int b = blockIdx.x, t = threadIdx.x;
  #pragma unroll
  for (int i=0;i<16;++i){
    int px = i*256 + t;
    float s = gray4[(size_t)(0*8+b)*4096 + px] + gray4[(size_t)(1*8+b)*4096 + px]
            + gray4[(size_t)(2*8+b)*4096 + px] + gray4[(size_t)(3*8+b)*4096 + px];
    gf[px] = s * (1.f/256.f);
  }
  __syncthreads();
  #pragma unroll
  for (int i=0;i<16;++i){
    int px = i*256 + t;
    int hh = px>>6, ww = px&63;
    float c = gf[px];
    float up = hh>0  ? gf[px-64] : 0.f;
    float dn = hh<63 ? gf[px+64] : 0.f;
    float lf = ww>0  ? gf[px-1]  : 0.f;
    float rt = ww<63 ? gf[px+1]  : 0.f;
    la[px] = fabsf(4.f*c - up - dn - lf - rt);
  }
  __syncthreads();
  float w1r[72], b1r[8];
  #pragma unroll
  for (int k=0;k<72;++k) w1r[k] = w1[k];
  #pragma unroll
  for (int j=0;j<8;++j) b1r[j] = b1[j];
  #pragma unroll
  for (int i=0;i<16;++i){
    int px = i*256 + t;
    int hh = px>>6, ww = px&63;
    float tap[9];
    #pragma unroll
    for (int dy=-1;dy<=1;++dy)
      #pragma unroll
      for (int dx=-1;dx<=1;++dx){
        int y=hh+dy, x2=ww+dx;
        tap[(dy+1)*3+dx+1] = (y>=0&&y<64&&x2>=0&&x2<64)? la[y*64+x2] : 0.f;
      }
    #pragma unroll
    for (int j=0;j<8;++j){
      float a = b1r[j];
      #pragma unroll
      for (int k=0;k<9;++k) a += w1r[j*9+k]*tap[k];
      hb[j*4096 + px] = f2b(fmaxf(a, 0.f));
    }
  }
  __syncthreads();
  float w2r[72], b20 = b2_[0];
  #pragma unroll
  for (int k=0;k<72;++k) w2r[k] = w2[k];
  #pragma unroll
  for (int i=0;i<16;++i){
    int px = i*256 + t;
    int hh = px>>6, ww = px&63;
    float a = b20;
    #pragma unroll
    for (int j=0;j<8;++j){
      #pragma unroll
      for (int dy=-1;dy<=1;++dy)
        #pragma unroll
        for (int dx=-1;dx<=1;++dx){
          int y=hh+dy, x2=ww+dx;
          if (y>=0&&y<64&&x2>=0&&x2<64) a += w2r[j*9+(dy+1)*3+(dx+1)]*b2f(hb[j*4096 + y*64+x2]);
        }
    }
    float sig = 1.f/(1.f+__expf(-a));
    sc2[(size_t)b*4096 + px] = 0.09016844f/(3.f - 2.f*sig);   // C^-0.5 * log2e / temp
  }
}

// ---------------- QKV GEMM: block owns one n-tile, loops all 12 W-tiles ----------------
// Q -> Q[n][c] row-major; K -> octet blocks Koct[b][m>>5][c>>3][m&31][8];
// V -> octet blocks Voct[b][m>>5][(m&31)>>3][c][m&7]
__global__ __launch_bounds__(256,2) void k_gemm_qkv(const unsigned short* __restrict__ Wg,
    const unsigned short* __restrict__ Xtg, const float* __restrict__ biasg,
    unsigned short* __restrict__ Qo, unsigned short* __restrict__ Ko, unsigned short* __restrict__ Vto){
  __shared__ unsigned short Xl[64*256];   // staged once per block
  __shared__ unsigned short Wl[64*256];   // re-staged per at-tile
  const int nt_ = blockIdx.x, b = blockIdx.y;
  const int n0 = nt_*64;
  stage_64x256(Xl, Xtg + ((size_t)(b*4096 + n0))*256, 256);
  const int t = threadIdx.x, w = t>>6, lane = t&63, lam = lane&15, lg = lane>>4;
  f32x4 zz = {0.f,0.f,0.f,0.f};
  for (int at=0; at<12; ++at){
    const int a0 = at*64;
    stage_64x256(Wl, Wg + (size_t)a0*256, 256);
    __syncthreads();                       // Wl (and Xl on first iter) staged
    f32x4 acc[4] = {zz,zz,zz,zz};
    #pragma unroll
    for (int u=0;u<8;++u){
      int ar = 16*w + lam;
      s16x8 af = *(const s16x8*)((const char*)Wl + ar*512 + ((64*u+16*lg) ^ ((ar&7)<<4)));
      #pragma unroll
      for (int ct=0;ct<4;++ct){
        int br = 16*ct + lam;
        s16x8 bf = *(const s16x8*)((const char*)Xl + br*512 + ((64*u+16*lg) ^ ((br&7)<<4)));
        acc[ct] = MFMA16(af, bf, acc[ct]);
      }
    }
    const int ob = a0 + 16*w + 4*lg;
    f32x4 bias4 = *(const f32x4*)(biasg + ob);
    #pragma unroll
    for (int ct=0;ct<4;++ct){
      int n = n0 + 16*ct + lam;
      us4 ov;
      #pragma unroll
      for (int r=0;r<4;++r) ov[r] = f2b(acc[ct][r] + bias4[r]);
      if (a0 < 256){
        *(us4*)(Qo + ((size_t)(b*4096 + n))*256 + ob) = ov;        // Q[n][c]
      } else if (a0 < 512){
        int c4 = ob - 256;
        size_t idx = (((size_t)(b*128 + (n>>5))*1024) + (c4>>3)*32 + (n&31))*8 + (c4&7);
        *(us4*)(Ko + idx) = ov;
      } else {
        int c0v = ob - 512;
        size_t base = ((size_t)(b*128 + (n>>5))*1024 + ((n&31)>>3)*256)*8 + (n&7);
        #pragma unroll
        for (int r=0;r<4;++r)
          Vto[base + (size_t)(c0v+r)*8] = ov[r];
      }
    }
    __syncthreads();                       // all waves done reading Wl before overwrite
  }
}

// ---------------- flash attention: R10 schedule (best known) ----------------
__global__ __launch_bounds__(512,2) void k_attn(const unsigned short* __restrict__ Qg,
    const unsigned short* __restrict__ Kg, const unsigned short* __restrict__ Vtg,
    const float* __restrict__ Sg, unsigned short* __restrict__ AOt){
  __shared__ __align__(16) char SL[132096];
  unsigned short* Kl = (unsigned short*)SL;             // [buf][grp] 16KB octet tiles
  unsigned short* Vl = (unsigned short*)(SL + 65536);
  float* mlb = (float*)(SL + 131072);                   // [4][32][2]
  float* Ob  = (float*)SL;                              // merge reuse [4][32][256] f32

  const int tid = threadIdx.x, w = tid>>6, lane = tid&63, l31 = lane&31, h = lane>>5;
  const int g = w>>2;                      // key-half group
  const int bid = blockIdx.x;
  const int b = bid&7, qt = bid>>3;        // XCD-major: batch pinned to XCD
  const int qbase = qt*128 + (w&3)*32;

  const unsigned short* KgB = Kg  + (size_t)b*128*8192;   // octet blocks of 8192 elems
  const unsigned short* VtB = Vtg + (size_t)b*128*8192;
  const float* SgB = Sg + (size_t)b*4096 + g*2048;

  // Q fragments (B-operand): lane q-col=l31, k-elems 16u+8h..+7
  s16x8 qf[16];
  {
    const unsigned short* qp = Qg + ((size_t)(b*4096 + qbase + l31))*256 + 8*h;
    #pragma unroll
    for (int u=0;u<16;++u) qf[u] = *(const s16x8*)(qp + 16*u);
  }
  f32x16 oa[8];
  #pragma unroll
  for (int nb=0;nb<8;++nb)
    #pragma unroll
    for (int i=0;i<16;++i) oa[nb][i]=0.f;
  float m_run = 0.f, l_run = 0.f;          // log2 domain; m=0 valid start (defer-bounded)

  #define KBUF(bu,gr) (Kl + ((bu)*2+(gr))*8192)
  #define VBUF(bu,gr) (Vl + ((bu)*2+(gr))*8192)

  stage16KB(KBUF(0,0), KgB);
  stage16KB(KBUF(0,1), KgB + (size_t)64*8192);
  stage16KB(VBUF(0,0), VtB);
  stage16KB(VBUF(0,1), VtB + (size_t)64*8192);
  __syncthreads();

  int cur = 0;
  for (int t=0; t<64; ++t){
    // stage(t+1) at loop top: full iteration to complete (R7/R10 schedule)
    if (t < 63){
      stage16KB(KBUF(cur^1,0), KgB + (size_t)(t+1)*8192);
      stage16KB(KBUF(cur^1,1), KgB + (size_t)(64+t+1)*8192);
      stage16KB(VBUF(cur^1,0), VtB + (size_t)(t+1)*8192);
      stage16KB(VBUF(cur^1,1), VtB + (size_t)(64+t+1)*8192);
    }
    const char* Kc = (const char*)KBUF(cur,g);
    const char* Vc = (const char*)VBUF(cur,g);

    // per-key temperature scales (log2-domain, from k_density)
    f32x4 sv[4];
    {
      const float* Sp = SgB + t*32;
      #pragma unroll
      for (int j=0;j<4;++j) sv[j] = *(const f32x4*)(Sp + 8*j + 4*h);
    }

    // S^T = K * Q^T : D col=q=l31, row=key (r&3)+8*(r>>2)+4h
    f32x16 st;
    #pragma unroll
    for (int i=0;i<16;++i) st[i]=0.f;
    __builtin_amdgcn_s_setprio(1);
    #pragma unroll
    for (int u=0;u<16;++u){
      s16x8 kf = *(const s16x8*)(Kc + (((2*u+h)*32 + l31)<<4));
      st = MFMA32(kf, qf[u], st);
    }
    __builtin_amdgcn_s_setprio(0);

    float pm[16];
    #pragma unroll
    for (int j=0;j<4;++j)
      #pragma unroll
      for (int i=0;i<4;++i) pm[4*j+i] = st[4*j+i]*sv[j][i];

    // max tree -> defer check -> single exp2
    float mx[8];
    #pragma unroll
    for (int i=0;i<8;++i) mx[i] = fmaxf(pm[i], pm[8+i]);
    #pragma unroll
    for (int i=0;i<4;++i) mx[i] = fmaxf(mx[i], mx[4+i]);
    float tmax = fmaxf(fmaxf(mx[0],mx[1]), fmaxf(mx[2],mx[3]));
    if (__any(tmax > m_run + 11.5415603f)){   // defer-max (rare)
      tmax = fmaxf(tmax, __shfl_xor(tmax, 32));
      float mnew = fmaxf(m_run, tmax);
      float fs = exp2f(m_run - mnew);
      m_run = mnew;
      l_run *= fs;
      float fr[16];
      #pragma unroll
      for (int r=0;r<16;++r) fr[r] = __shfl(fs, (r&3)+8*(r>>2)+4*h);
      #pragma unroll
      for (int nb=0;nb<8;++nb)
        #pragma unroll
        for (int r=0;r<16;++r) oa[nb][r] *= fr[r];
    }
    float pe[16];
    #pragma unroll
    for (int i=0;i<16;++i) pe[i] = exp2f(pm[i] - m_run);
    {
      float sm[8];
      #pragma unroll
      for (int i=0;i<8;++i) sm[i] = pe[i] + pe[8+i];
      #pragma unroll
      for (int i=0;i<4;++i) sm[i] += sm[4+i];
      float rs = (sm[0]+sm[1])+(sm[2]+sm[3]);
      rs += __shfl_xor(rs, 32);
      l_run += rs;
    }

    // pack P to bf16 quads via cvt_pk: pq[2j],pq[2j+1] = keys 8j+4h+0..3
    unsigned pq[8];
    #pragma unroll
    for (int j=0;j<4;++j){
      pq[2*j]   = cvt_pk_bf16(pe[4*j],   pe[4*j+1]);
      pq[2*j+1] = cvt_pk_bf16(pe[4*j+2], pe[4*j+3]);
    }

    // PV: A-frag assembled in-register via cross-h swap; B=V^T octet tile
    __builtin_amdgcn_s_setprio(1);
    #pragma unroll
    for (int ks=0;ks<2;++ks){
      const int j0 = 2*ks, j1 = 2*ks+1;
      unsigned s0 = h ? pq[2*j0]   : pq[2*j1];
      unsigned s1 = h ? pq[2*j0+1] : pq[2*j1+1];
      unsigned r0 = (unsigned)__shfl_xor((int)s0, 32);
      unsigned r1 = (unsigned)__shfl_xor((int)s1, 32);
      union { unsigned u[4]; s16x8 v; } pa;
      pa.u[0] = h ? r0 : pq[2*j0];
      pa.u[1] = h ? r1 : pq[2*j0+1];
      pa.u[2] = h ? pq[2*j1]   : r0;
      pa.u[3] = h ? pq[2*j1+1] : r1;
      #pragma unroll
      for (int nb=0;nb<8;++nb){
        s16x8 vf = *(const s16x8*)(Vc + (((2*ks+h)*256 + 32*nb + l31)<<4));
        oa[nb] = MFMA32(pa.v, vf, oa[nb]);
      }
    }
    __builtin_amdgcn_s_setprio(0);

    __syncthreads();
    cur ^= 1;
  }

  // ---- in-block merge of the two key-halves (log2-domain m) ----
  if (g == 1){
    if (h == 0){
      mlb[((w-4)*32 + l31)*2]   = m_run;
      mlb[((w-4)*32 + l31)*2+1] = l_run;
    }
    float* Ow = Ob + (size_t)(w-4)*32*256;
    #pragma unroll
    for (int nb=0;nb<8;++nb)
      #pragma unroll
      for (int r=0;r<16;++r){
        int qr = (r&3)+8*(r>>2)+4*h;
        Ow[qr*256 + 32*nb + l31] = oa[nb][r];
      }
  }
  __syncthreads();
  if (g == 0){
    const float* Or = Ob + (size_t)w*32*256;
    #pragma unroll
    for (int r=0;r<16;++r){
      int qr = (r&3)+8*(r>>2)+4*h;
      float m0r = __shfl(m_run, qr);
      float l0r = __shfl(l_run, qr);
      float m1r = mlb[(w*32+qr)*2];
      float l1r = mlb[(w*32+qr)*2+1];
      float M = fmaxf(m0r, m1r);
      float a0 = exp2f(m0r - M), a1 = exp2f(m1r - M);
      float inv = 1.f/(l0r*a0 + l1r*a1);
      a0 *= inv; a1 *= inv;
      unsigned short* dst = AOt + ((size_t)(b*4096 + qbase + qr))*256 + l31;
      #pragma unroll
      for (int nb=0;nb<8;++nb){
        float v = oa[nb][r]*a0 + Or[qr*256 + 32*nb + l31]*a1;
        dst[32*nb] = f2b(v);
      }
    }
  }
  #undef KBUF
  #undef VBUF
}

// ---------------- OUT GEMM: block owns one a-tile, loops all 4 Wo-tiles ----------------
__global__ __launch_bounds__(256,2) void k_gemm_out(const unsigned short* __restrict__ Ag,
    const unsigned short* __restrict__ Bg, const float* __restrict__ biasg,
    const float* __restrict__ xg, float* __restrict__ outg){
  __shared__ unsigned short Al[64*256];   // staged once
  __shared__ unsigned short Bl[64*256];   // per-bt tile
  const int at = blockIdx.x, b = blockIdx.y;
  const int a0 = at*64;
  stage_64x256(Al, Ag + ((size_t)(b*4096 + a0))*256, 256);
  const int t = threadIdx.x, w = t>>6, lane = t&63, lam = lane&15, lg = lane>>4;
  f32x4 zz = {0.f,0.f,0.f,0.f};
  for (int bt=0; bt<4; ++bt){
    const int o0 = bt*64;
    stage_64x256(Bl, Bg + (size_t)o0*256, 256);
    __syncthreads();
    f32x4 acc[4] = {zz,zz,zz,zz};
    #pragma unroll
    for (int u=0;u<8;++u){
      int ar = 16*w + lam;
      s16x8 af = *(const s16x8*)((const char*)Al + ar*512 + ((64*u+16*lg) ^ ((ar&7)<<4)));
      #pragma unroll
      for (int ct=0;ct<4;++ct){
        int br = 16*ct + lam;
        s16x8 bf = *(const s16x8*)((const char*)Bl + br*512 + ((64*u+16*lg) ^ ((br&7)<<4)));
        acc[ct] = MFMA16(af, bf, acc[ct]);
      }
    }
    #pragma unroll
    for (int ct=0;ct<4;++ct){
      int o = o0 + 16*ct + lam;
      float ob_ = biasg[o];
      size_t base = ((size_t)(b*256 + o))*4096 + a0 + 16*w + 4*lg;
      f32x4 xv = *(const f32x4*)(xg + base);
      f32x4 ov;
      #pragma unroll
      for (int r=0;r<4;++r) ov[r] = acc[ct][r] + ob_ + xv[r];
      *(f32x4*)(outg + base) = ov;
    }
    __syncthreads();
  }
}

extern "C" void kernel_launch(void* const* d_in, const int* in_sizes, int n_in,
                              void* d_out, int out_size, void* d_ws, size_t ws_size,
                              hipStream_t stream){
  const float* x     = (const float*)d_in[0];
  const float* qkv_w = (const float*)d_in[1];
  const float* qkv_b = (const float*)d_in[2];
  const float* out_w = (const float*)d_in[3];
  const float* out_b = (const float*)d_in[4];
  const float* d1_w  = (const float*)d_in[5];
  const float* d1_b  = (const float*)d_in[6];
  const float* d2_w  = (const float*)d_in[7];
  const float* d2_b  = (const float*)d_in[8];
  float* out = (float*)d_out;

  char* p = (char*)d_ws;
  const size_t BIG = (size_t)8*4096*256*2;
  unsigned short* Xt = (unsigned short*)p; p += BIG;   // reused as AOt after QKV GEMM
  unsigned short* Q  = (unsigned short*)p; p += BIG;
  unsigned short* K  = (unsigned short*)p; p += BIG;
  unsigned short* Vt = (unsigned short*)p; p += BIG;
  unsigned short* Wq = (unsigned short*)p; p += (size_t)768*256*2;
  unsigned short* Wo = (unsigned short*)p; p += (size_t)256*256*2;
  float* gray4 = (float*)p; p += (size_t)4*8*4096*4;
  float* sc    = (float*)p; p += (size_t)8*4096*4;

  k_cvt      <<<dim3(192),    256, 0, stream>>>(qkv_w, Wq);
  k_cvt      <<<dim3(64),     256, 0, stream>>>(out_w, Wo);
  k_transpose<<<dim3(64,4,8), 256, 0, stream>>>(x, Xt, gray4);
  k_density  <<<dim3(8),      256, 0, stream>>>(gray4, d1_w, d1_b, d2_w, d2_b, sc);
  k_gemm_qkv <<<dim3(64,8),   256, 0, stream>>>(Wq, Xt, qkv_b, Q, K, Vt);
  k_attn     <<<dim3(256),    512, 0, stream>>>(Q, K, Vt, sc, Xt);
  k_gemm_out <<<dim3(64,8),   256, 0, stream>>>(Xt, Wo, out_b, x, out);
}